// Round 9
// baseline (158.291 us; speedup 1.0000x reference)
//
#include <hip/hip_runtime.h>
#include <math.h>

typedef __attribute__((ext_vector_type(2))) float f32x2;

#define BB 4
#define HH 2048
#define WW 128
#define HP (HH + 2)   // 2050
#define WP (WW + 2)   // 130
#define PP 128        // pooled size
#define ROWS 4
#define SROWS 13      // staged xp rows per k_deform block

#define BORDER_PER_B (2 * WP + 2 * (HP - 2))   // 4356

// ---------------------------------------------------------------------------
// Kernel 1: border-zero of xp (fused) + adaptive avg pool + 1x1 conv + sigmoid
// ---------------------------------------------------------------------------
__global__ void k_fm(const float* __restrict__ rgb, const float* __restrict__ w_fm,
                     float* __restrict__ fm, float4* __restrict__ xp) {
    int j = threadIdx.x;              // 0..127
    int bi = blockIdx.x;              // b*128 + i
    int tid = bi * 128 + j;

    if (tid < BB * BORDER_PER_B) {
        int b = tid / BORDER_PER_B;
        int r = tid - b * BORDER_PER_B;
        int row, col;
        if (r < WP)          { row = 0;      col = r; }
        else if (r < 2 * WP) { row = HP - 1; col = r - WP; }
        else {
            int q = r - 2 * WP;
            row = 1 + (q >> 1);
            col = (q & 1) ? (WP - 1) : 0;
        }
        xp[((size_t)b * HP + row) * WP + col] = make_float4(0.f, 0.f, 0.f, 0.f);
    }

    int b = bi >> 7, i = bi & 127;
    const float* r0 = rgb + ((size_t)(b * 2 + 0) * HH + (size_t)i * 16) * WW + j;
    const float* r1 = rgb + ((size_t)(b * 2 + 1) * HH + (size_t)i * 16) * WW + j;
    float s0 = 0.f, s1 = 0.f;
#pragma unroll
    for (int a = 0; a < 16; ++a) { s0 += r0[a * WW]; s1 += r1[a * WW]; }
    s0 *= (1.f / 16.f); s1 *= (1.f / 16.f);
    float f0 = w_fm[0] * s0 + w_fm[1] * s1;
    float f1 = w_fm[2] * s0 + w_fm[3] * s1;
    fm[((size_t)(b * 2 + 0) * PP + i) * PP + j] = 1.f / (1.f + expf(-f0));
    fm[((size_t)(b * 2 + 1) * PP + i) * PP + j] = 1.f / (1.f + expf(-f1));
}

// ---------------------------------------------------------------------------
// Kernel 2: mat = rgb @ fm + rgb (per b,c), fs = w_fs @ mat,
//           pack xp cell = float4 (sar0,sar1,fs0,fs1).  (R6-proven, ROWS=4)
// ---------------------------------------------------------------------------
__global__ __launch_bounds__(128) void k_mat(
        const float* __restrict__ rgb, const float* __restrict__ sar,
        const float* __restrict__ w_fs, const float* __restrict__ fm,
        float* __restrict__ xp) {
    int w = threadIdx.x;              // 0..127
    int blk = blockIdx.x;
    int b = blk / (HH / ROWS);
    int h0 = (blk % (HH / ROWS)) * ROWS;

    const float* rg0 = rgb + ((size_t)(b * 2 + 0) * HH + h0) * WW;  // uniform base
    const float* rg1 = rgb + ((size_t)(b * 2 + 1) * HH + h0) * WW;
    const float* fm0 = fm + (size_t)(b * 2 + 0) * PP * PP;
    const float* fm1 = fm + (size_t)(b * 2 + 1) * PP * PP;

    float acc0[ROWS], acc1[ROWS];
#pragma unroll
    for (int r = 0; r < ROWS; ++r) {                 // residual term
        acc0[r] = rg0[r * WW + w];
        acc1[r] = rg1[r * WW + w];
    }

#pragma unroll 4
    for (int k4 = 0; k4 < PP; k4 += 4) {
        float f0[4], f1[4];
#pragma unroll
        for (int t = 0; t < 4; ++t) {
            f0[t] = fm0[(size_t)(k4 + t) * PP + w];  // coalesced vector load
            f1[t] = fm1[(size_t)(k4 + t) * PP + w];
        }
#pragma unroll
        for (int r = 0; r < ROWS; ++r) {
            float4 a0 = *(const float4*)(rg0 + r * WW + k4);   // uniform -> s_load
            float4 a1 = *(const float4*)(rg1 + r * WW + k4);
            acc0[r] += a0.x * f0[0] + a0.y * f0[1] + a0.z * f0[2] + a0.w * f0[3];
            acc1[r] += a1.x * f1[0] + a1.y * f1[1] + a1.z * f1[2] + a1.w * f1[3];
        }
    }

    float wa = w_fs[0], wb = w_fs[1], wc = w_fs[2], wd = w_fs[3];
#pragma unroll
    for (int r = 0; r < ROWS; ++r) {
        float m0 = acc0[r], m1 = acc1[r];
        float fs0 = wa * m0 + wb * m1;
        float fs1 = wc * m0 + wd * m1;
        float s0 = sar[((size_t)(b * 2 + 0) * HH + (h0 + r)) * WW + w];
        float s1 = sar[((size_t)(b * 2 + 1) * HH + (h0 + r)) * WW + w];
        float4 v = make_float4(s0, s1, fs0, fs1);
        *(float4*)(xp + (((size_t)b * HP + (h0 + r + 1)) * WP + (w + 1)) * 4) = v;
    }
}

// ---------------------------------------------------------------------------
// Kernel 3: offset conv (pk_fma, r-outer) + deformable bilinear + deform conv.
// Block = 4 output rows of one batch; xp rows [ylo, yhi] staged in LDS (27KB).
// All nb + bilinear gathers hit LDS; exact global fallback for |off|>3
// (practically never taken). Interp/combine packed f32x2 over channel pairs.
// XCD swizzle: same-XCD blocks cover contiguous rows -> staging halo = L2 hit.
// ---------------------------------------------------------------------------
__global__ __launch_bounds__(256, 2) void k_deform(
        const float* __restrict__ w_p, const float* __restrict__ b_p,
        const float* __restrict__ w_dc, const float* __restrict__ xp,
        float* __restrict__ out) {
    __shared__ float4 lds[SROWS * WP];          // 13*130*16B = 27040 B

    int bid = blockIdx.x;                       // 0..2047
    int swz = (bid & 7) * 256 + (bid >> 3);     // XCD-contiguous row spans
    int b = swz >> 9;                           // 512 blocks per batch
    int h0 = (swz & 511) * 4;                   // output rows h0..h0+3
    int tid = threadIdx.x;
    int w = tid & 127;
    int h = h0 + ((tid >> 7) << 1);             // this thread: rows h, h+1

    const float4* xpb = (const float4*)xp + (size_t)b * HP * WP;

    int ylo = h0 - 3; if (ylo < 0) ylo = 0;
    int yhi = ylo + SROWS - 1; if (yhi > HP - 1) yhi = HP - 1;
    int cells = (yhi - ylo + 1) * WP;
    for (int i = tid; i < cells; i += 256)
        lds[i] = xpb[(ylo + i / WP) * WP + (i % WP)];
    __syncthreads();

    // 4 rows x 3 cols neighborhood from LDS
    float4 nb4[4][3];
#pragma unroll
    for (int dy = 0; dy < 4; ++dy)
#pragma unroll
        for (int dx = 0; dx < 3; ++dx)
            nb4[dy][dx] = lds[(h - ylo + dy) * WP + (w + dx)];

    // pixel-pair vectors, formed once, static indexing
    f32x2 prs[3][3][4];
#pragma unroll
    for (int ky = 0; ky < 3; ++ky)
#pragma unroll
        for (int kx = 0; kx < 3; ++kx) {
            prs[ky][kx][0] = (f32x2){nb4[ky][kx].x, nb4[ky + 1][kx].x};
            prs[ky][kx][1] = (f32x2){nb4[ky][kx].y, nb4[ky + 1][kx].y};
            prs[ky][kx][2] = (f32x2){nb4[ky][kx].z, nb4[ky + 1][kx].z};
            prs[ky][kx][3] = (f32x2){nb4[ky][kx].w, nb4[ky + 1][kx].w};
        }

    // ---- offset conv: r-outer, local accumulator -> v_pk_fma_f32 ----
    f32x2 off2[18];
#pragma unroll
    for (int r = 0; r < 18; ++r) {
        float bias = b_p[r];                    // uniform -> s_load
        f32x2 s = (f32x2){bias, bias};
#pragma unroll
        for (int ky = 0; ky < 3; ++ky)
#pragma unroll
            for (int kx = 0; kx < 3; ++kx) {
                const float* wr = w_p + r * 36 + ky * 3 + kx;  // uniform s_load
                s += wr[0] * prs[ky][kx][0] + wr[9] * prs[ky][kx][1]
                   + wr[18] * prs[ky][kx][2] + wr[27] * prs[ky][kx][3];
            }
        off2[r] = s;
    }

    f32x2 accv0[2] = {(f32x2){0.f, 0.f}, (f32x2){0.f, 0.f}};
    f32x2 accv1[2] = {(f32x2){0.f, 0.f}, (f32x2){0.f, 0.f}};
#pragma unroll
    for (int n = 0; n < 9; ++n) {
        int pny = n / 3 - 1;
        int pnx = n % 3 - 1;
        // packed coordinates for the pixel pair
        f32x2 py2 = (f32x2){(float)(h + 1 + pny), (float)(h + 2 + pny)} + off2[n];
        f32x2 px2 = (float)(w + 1 + pnx) + off2[9 + n];
        f32x2 fy2 = {floorf(py2.x), floorf(py2.y)};
        f32x2 fx2 = {floorf(px2.x), floorf(px2.y)};
        f32x2 y0f = {fminf(fmaxf(fy2.x, 0.f), (float)(HP - 1)),
                     fminf(fmaxf(fy2.y, 0.f), (float)(HP - 1))};
        f32x2 y1f = {fminf(fmaxf(fy2.x + 1.f, 0.f), (float)(HP - 1)),
                     fminf(fmaxf(fy2.y + 1.f, 0.f), (float)(HP - 1))};
        f32x2 x0f = {fminf(fmaxf(fx2.x, 0.f), (float)(WP - 1)),
                     fminf(fmaxf(fx2.y, 0.f), (float)(WP - 1))};
        f32x2 x1f = {fminf(fmaxf(fx2.x + 1.f, 0.f), (float)(WP - 1)),
                     fminf(fmaxf(fx2.y + 1.f, 0.f), (float)(WP - 1))};
        f32x2 pyc = {fminf(fmaxf(py2.x, 0.f), (float)(HP - 1)),
                     fminf(fmaxf(py2.y, 0.f), (float)(HP - 1))};
        f32x2 pxc = {fminf(fmaxf(px2.x, 0.f), (float)(WP - 1)),
                     fminf(fmaxf(px2.y, 0.f), (float)(WP - 1))};
        f32x2 ay = 1.f + (y0f - pyc);
        f32x2 by = 1.f - (y1f - pyc);
        f32x2 ax = 1.f + (x0f - pxc);
        f32x2 bx = 1.f - (x1f - pxc);
        f32x2 glt = ay * ax, grb = by * bx, glb = ay * bx, grt = by * ax;

        // deform-conv weight pairs (uniform), invariant over p
        f32x2 wxy0 = {w_dc[0 * 36 + 0 * 9 + n], w_dc[0 * 36 + 1 * 9 + n]};
        f32x2 wzw0 = {w_dc[0 * 36 + 2 * 9 + n], w_dc[0 * 36 + 3 * 9 + n]};
        f32x2 wxy1 = {w_dc[1 * 36 + 0 * 9 + n], w_dc[1 * 36 + 1 * 9 + n]};
        f32x2 wzw1 = {w_dc[1 * 36 + 2 * 9 + n], w_dc[1 * 36 + 3 * 9 + n]};

#pragma unroll
        for (int p = 0; p < 2; ++p) {
            int y0 = (int)(p ? y0f.y : y0f.x);
            int y1 = (int)(p ? y1f.y : y1f.x);
            int x0 = (int)(p ? x0f.y : x0f.x);
            int x1 = (int)(p ? x1f.y : x1f.x);
            f32x2 glt2 = p ? (f32x2){glt.y, glt.y} : (f32x2){glt.x, glt.x};
            f32x2 grb2 = p ? (f32x2){grb.y, grb.y} : (f32x2){grb.x, grb.x};
            f32x2 glb2 = p ? (f32x2){glb.y, glb.y} : (f32x2){glb.x, glb.x};
            f32x2 grt2 = p ? (f32x2){grt.y, grt.y} : (f32x2){grt.x, grt.x};

            float4 v_lt, v_rb, v_lb, v_rt;
            if (y0 >= ylo && y1 <= yhi) {       // LDS fast path (always in practice)
                int r0 = (y0 - ylo) * WP, r1 = (y1 - ylo) * WP;
                v_lt = lds[r0 + x0];
                v_rb = lds[r1 + x1];
                v_lb = lds[r0 + x1];
                v_rt = lds[r1 + x0];
            } else {                            // exact global fallback
                int r0 = y0 * WP, r1 = y1 * WP;
                v_lt = xpb[r0 + x0];
                v_rb = xpb[r1 + x1];
                v_lb = xpb[r0 + x1];
                v_rt = xpb[r1 + x0];
            }

            f32x2 vxy = glt2 * (f32x2){v_lt.x, v_lt.y}
                      + grb2 * (f32x2){v_rb.x, v_rb.y}
                      + glb2 * (f32x2){v_lb.x, v_lb.y}
                      + grt2 * (f32x2){v_rt.x, v_rt.y};
            f32x2 vzw = glt2 * (f32x2){v_lt.z, v_lt.w}
                      + grb2 * (f32x2){v_rb.z, v_rb.w}
                      + glb2 * (f32x2){v_lb.z, v_lb.w}
                      + grt2 * (f32x2){v_rt.z, v_rt.w};

            accv0[p] += vxy * wxy0 + vzw * wzw0;
            accv1[p] += vxy * wxy1 + vzw * wzw1;
        }
    }
#pragma unroll
    for (int p = 0; p < 2; ++p) {
        out[((size_t)(b * 2 + 0) * HH + (h + p)) * WW + w] = accv0[p].x + accv0[p].y;
        out[((size_t)(b * 2 + 1) * HH + (h + p)) * WW + w] = accv1[p].x + accv1[p].y;
    }
}

// ---------------------------------------------------------------------------
extern "C" void kernel_launch(void* const* d_in, const int* in_sizes, int n_in,
                              void* d_out, int out_size, void* d_ws, size_t ws_size,
                              hipStream_t stream) {
    const float* rgb  = (const float*)d_in[0];
    const float* sar  = (const float*)d_in[1];
    const float* w_fm = (const float*)d_in[2];
    const float* w_fs = (const float*)d_in[3];
    const float* w_p  = (const float*)d_in[4];
    const float* b_p  = (const float*)d_in[5];
    const float* w_dc = (const float*)d_in[6];
    float* out = (float*)d_out;

    // ws layout: fm [131072 f32] | xp [B*HP*WP float4]
    float* ws = (float*)d_ws;
    float* fm = ws;
    float* xp = ws + 131072;                           // 16B aligned

    k_fm<<<BB * 128, 128, 0, stream>>>(rgb, w_fm, fm, (float4*)xp);
    k_mat<<<BB * (HH / ROWS), 128, 0, stream>>>(rgb, sar, w_fs, fm, xp);
    k_deform<<<(BB * (HH / 2) * WW) / 256, 256, 0, stream>>>(w_p, b_p, w_dc, xp, out);
}

// Round 10
// 69.060 us; speedup vs baseline: 2.2921x; 2.2921x over previous
//
#include <hip/hip_runtime.h>
#include <math.h>

typedef __attribute__((ext_vector_type(2))) float f32x2;

#define BB 4
#define HH 2048
#define WW 128
#define HP (HH + 2)   // 2050
#define WP (WW + 2)   // 130
#define PP 128        // pooled size
#define ROWS 4

#define BORDER_PER_B (2 * WP + 2 * (HP - 2))   // 4356

// ---------------------------------------------------------------------------
// Kernel 1: border-zero of xp (fused) + adaptive avg pool + 1x1 conv + sigmoid
// ---------------------------------------------------------------------------
__global__ void k_fm(const float* __restrict__ rgb, const float* __restrict__ w_fm,
                     float* __restrict__ fm, float4* __restrict__ xp) {
    int j = threadIdx.x;              // 0..127
    int bi = blockIdx.x;              // b*128 + i
    int tid = bi * 128 + j;

    if (tid < BB * BORDER_PER_B) {
        int b = tid / BORDER_PER_B;
        int r = tid - b * BORDER_PER_B;
        int row, col;
        if (r < WP)          { row = 0;      col = r; }
        else if (r < 2 * WP) { row = HP - 1; col = r - WP; }
        else {
            int q = r - 2 * WP;
            row = 1 + (q >> 1);
            col = (q & 1) ? (WP - 1) : 0;
        }
        xp[((size_t)b * HP + row) * WP + col] = make_float4(0.f, 0.f, 0.f, 0.f);
    }

    int b = bi >> 7, i = bi & 127;
    const float* r0 = rgb + ((size_t)(b * 2 + 0) * HH + (size_t)i * 16) * WW + j;
    const float* r1 = rgb + ((size_t)(b * 2 + 1) * HH + (size_t)i * 16) * WW + j;
    float s0 = 0.f, s1 = 0.f;
#pragma unroll
    for (int a = 0; a < 16; ++a) { s0 += r0[a * WW]; s1 += r1[a * WW]; }
    s0 *= (1.f / 16.f); s1 *= (1.f / 16.f);
    float f0 = w_fm[0] * s0 + w_fm[1] * s1;
    float f1 = w_fm[2] * s0 + w_fm[3] * s1;
    fm[((size_t)(b * 2 + 0) * PP + i) * PP + j] = 1.f / (1.f + expf(-f0));
    fm[((size_t)(b * 2 + 1) * PP + i) * PP + j] = 1.f / (1.f + expf(-f1));
}

// ---------------------------------------------------------------------------
// Kernel 2: mat = rgb @ fm + rgb (per b,c), fs = w_fs @ mat,
//           pack xp cell = float4 (sar0,sar1,fs0,fs1).  (R6-proven, ROWS=4)
// ---------------------------------------------------------------------------
__global__ __launch_bounds__(128) void k_mat(
        const float* __restrict__ rgb, const float* __restrict__ sar,
        const float* __restrict__ w_fs, const float* __restrict__ fm,
        float* __restrict__ xp) {
    int w = threadIdx.x;              // 0..127
    int blk = blockIdx.x;
    int b = blk / (HH / ROWS);
    int h0 = (blk % (HH / ROWS)) * ROWS;

    const float* rg0 = rgb + ((size_t)(b * 2 + 0) * HH + h0) * WW;  // uniform base
    const float* rg1 = rgb + ((size_t)(b * 2 + 1) * HH + h0) * WW;
    const float* fm0 = fm + (size_t)(b * 2 + 0) * PP * PP;
    const float* fm1 = fm + (size_t)(b * 2 + 1) * PP * PP;

    float acc0[ROWS], acc1[ROWS];
#pragma unroll
    for (int r = 0; r < ROWS; ++r) {                 // residual term
        acc0[r] = rg0[r * WW + w];
        acc1[r] = rg1[r * WW + w];
    }

#pragma unroll 4
    for (int k4 = 0; k4 < PP; k4 += 4) {
        float f0[4], f1[4];
#pragma unroll
        for (int t = 0; t < 4; ++t) {
            f0[t] = fm0[(size_t)(k4 + t) * PP + w];  // coalesced vector load
            f1[t] = fm1[(size_t)(k4 + t) * PP + w];
        }
#pragma unroll
        for (int r = 0; r < ROWS; ++r) {
            float4 a0 = *(const float4*)(rg0 + r * WW + k4);   // uniform -> s_load
            float4 a1 = *(const float4*)(rg1 + r * WW + k4);
            acc0[r] += a0.x * f0[0] + a0.y * f0[1] + a0.z * f0[2] + a0.w * f0[3];
            acc1[r] += a1.x * f1[0] + a1.y * f1[1] + a1.z * f1[2] + a1.w * f1[3];
        }
    }

    float wa = w_fs[0], wb = w_fs[1], wc = w_fs[2], wd = w_fs[3];
#pragma unroll
    for (int r = 0; r < ROWS; ++r) {
        float m0 = acc0[r], m1 = acc1[r];
        float fs0 = wa * m0 + wb * m1;
        float fs1 = wc * m0 + wd * m1;
        float s0 = sar[((size_t)(b * 2 + 0) * HH + (h0 + r)) * WW + w];
        float s1 = sar[((size_t)(b * 2 + 1) * HH + (h0 + r)) * WW + w];
        float4 v = make_float4(s0, s1, fs0, fs1);
        *(float4*)(xp + (((size_t)b * HP + (h0 + r + 1)) * WP + (w + 1)) * 4) = v;
    }
}

// ---------------------------------------------------------------------------
// Kernel 3: offset conv (pk_fma, r-outer) + deformable bilinear + deform conv.
// 2 px/thread. NO LDS (R9 lesson: dual-path LDS|global gather bodies spill).
// blockIdx.y = batch -> xp/out bases are WAVE-UNIFORM (SGPR) and all gathers
// use 32-bit cell indices (saddr form, ~2 inst/load instead of ~5).
// __launch_bounds__(256,4): 128-VGPR cap, room for load pipelining.
// ---------------------------------------------------------------------------
__global__ __launch_bounds__(256, 4) void k_deform(
        const float* __restrict__ w_p, const float* __restrict__ b_p,
        const float* __restrict__ w_dc, const float* __restrict__ xp,
        float* __restrict__ out) {
    int b = blockIdx.y;                         // batch (uniform)
    int h0 = blockIdx.x * 4;                    // output rows h0..h0+3
    int tid = threadIdx.x;
    int w = tid & 127;
    int h = h0 + ((tid >> 7) << 1);             // this thread: rows h, h+1

    const float4* xpb = (const float4*)xp + (size_t)b * HP * WP;   // SGPR base
    float* outb = out + (size_t)(b * 2) * HH * WW;                 // SGPR base

    // 4 rows x 3 cols neighborhood (32-bit cell indices off SGPR base)
    float4 nb4[4][3];
#pragma unroll
    for (int dy = 0; dy < 4; ++dy)
#pragma unroll
        for (int dx = 0; dx < 3; ++dx)
            nb4[dy][dx] = xpb[(h + dy) * WP + (w + dx)];

    // pixel-pair vectors, formed once, static indexing
    f32x2 prs[3][3][4];
#pragma unroll
    for (int ky = 0; ky < 3; ++ky)
#pragma unroll
        for (int kx = 0; kx < 3; ++kx) {
            prs[ky][kx][0] = (f32x2){nb4[ky][kx].x, nb4[ky + 1][kx].x};
            prs[ky][kx][1] = (f32x2){nb4[ky][kx].y, nb4[ky + 1][kx].y};
            prs[ky][kx][2] = (f32x2){nb4[ky][kx].z, nb4[ky + 1][kx].z};
            prs[ky][kx][3] = (f32x2){nb4[ky][kx].w, nb4[ky + 1][kx].w};
        }

    // ---- offset conv: r-outer, local accumulator -> v_pk_fma_f32 ----
    f32x2 off2[18];
#pragma unroll
    for (int r = 0; r < 18; ++r) {
        float bias = b_p[r];                    // uniform -> s_load
        f32x2 s = (f32x2){bias, bias};
#pragma unroll
        for (int ky = 0; ky < 3; ++ky)
#pragma unroll
            for (int kx = 0; kx < 3; ++kx) {
                const float* wr = w_p + r * 36 + ky * 3 + kx;  // uniform s_load
                s += wr[0] * prs[ky][kx][0] + wr[9] * prs[ky][kx][1]
                   + wr[18] * prs[ky][kx][2] + wr[27] * prs[ky][kx][3];
            }
        off2[r] = s;
    }

    f32x2 accv0[2] = {(f32x2){0.f, 0.f}, (f32x2){0.f, 0.f}};
    f32x2 accv1[2] = {(f32x2){0.f, 0.f}, (f32x2){0.f, 0.f}};
#pragma unroll
    for (int n = 0; n < 9; ++n) {
        int pny = n / 3 - 1;
        int pnx = n % 3 - 1;
        // packed coordinates for the pixel pair
        f32x2 py2 = (f32x2){(float)(h + 1 + pny), (float)(h + 2 + pny)} + off2[n];
        f32x2 px2 = (float)(w + 1 + pnx) + off2[9 + n];
        f32x2 fy2 = {floorf(py2.x), floorf(py2.y)};
        f32x2 fx2 = {floorf(px2.x), floorf(px2.y)};
        f32x2 y0f = {fminf(fmaxf(fy2.x, 0.f), (float)(HP - 1)),
                     fminf(fmaxf(fy2.y, 0.f), (float)(HP - 1))};
        f32x2 y1f = {fminf(fmaxf(fy2.x + 1.f, 0.f), (float)(HP - 1)),
                     fminf(fmaxf(fy2.y + 1.f, 0.f), (float)(HP - 1))};
        f32x2 x0f = {fminf(fmaxf(fx2.x, 0.f), (float)(WP - 1)),
                     fminf(fmaxf(fx2.y, 0.f), (float)(WP - 1))};
        f32x2 x1f = {fminf(fmaxf(fx2.x + 1.f, 0.f), (float)(WP - 1)),
                     fminf(fmaxf(fx2.y + 1.f, 0.f), (float)(WP - 1))};
        f32x2 pyc = {fminf(fmaxf(py2.x, 0.f), (float)(HP - 1)),
                     fminf(fmaxf(py2.y, 0.f), (float)(HP - 1))};
        f32x2 pxc = {fminf(fmaxf(px2.x, 0.f), (float)(WP - 1)),
                     fminf(fmaxf(px2.y, 0.f), (float)(WP - 1))};
        f32x2 ay = 1.f + (y0f - pyc);
        f32x2 by = 1.f - (y1f - pyc);
        f32x2 ax = 1.f + (x0f - pxc);
        f32x2 bx = 1.f - (x1f - pxc);
        f32x2 glt = ay * ax, grb = by * bx, glb = ay * bx, grt = by * ax;

        // deform-conv weight pairs (uniform s_load), invariant over p
        f32x2 wxy0 = {w_dc[0 * 36 + 0 * 9 + n], w_dc[0 * 36 + 1 * 9 + n]};
        f32x2 wzw0 = {w_dc[0 * 36 + 2 * 9 + n], w_dc[0 * 36 + 3 * 9 + n]};
        f32x2 wxy1 = {w_dc[1 * 36 + 0 * 9 + n], w_dc[1 * 36 + 1 * 9 + n]};
        f32x2 wzw1 = {w_dc[1 * 36 + 2 * 9 + n], w_dc[1 * 36 + 3 * 9 + n]};

#pragma unroll
        for (int p = 0; p < 2; ++p) {           // p is compile-time constant
            int y0 = (int)(p ? y0f.y : y0f.x);
            int y1 = (int)(p ? y1f.y : y1f.x);
            int x0 = (int)(p ? x0f.y : x0f.x);
            int x1 = (int)(p ? x1f.y : x1f.x);
            f32x2 glt2 = p ? (f32x2){glt.y, glt.y} : (f32x2){glt.x, glt.x};
            f32x2 grb2 = p ? (f32x2){grb.y, grb.y} : (f32x2){grb.x, grb.x};
            f32x2 glb2 = p ? (f32x2){glb.y, glb.y} : (f32x2){glb.x, glb.x};
            f32x2 grt2 = p ? (f32x2){grt.y, grt.y} : (f32x2){grt.x, grt.x};

            int r0 = y0 * WP, r1 = y1 * WP;     // 32-bit cell indices
            float4 v_lt = xpb[r0 + x0];
            float4 v_rb = xpb[r1 + x1];
            float4 v_lb = xpb[r0 + x1];
            float4 v_rt = xpb[r1 + x0];

            f32x2 vxy = glt2 * (f32x2){v_lt.x, v_lt.y}
                      + grb2 * (f32x2){v_rb.x, v_rb.y}
                      + glb2 * (f32x2){v_lb.x, v_lb.y}
                      + grt2 * (f32x2){v_rt.x, v_rt.y};
            f32x2 vzw = glt2 * (f32x2){v_lt.z, v_lt.w}
                      + grb2 * (f32x2){v_rb.z, v_rb.w}
                      + glb2 * (f32x2){v_lb.z, v_lb.w}
                      + grt2 * (f32x2){v_rt.z, v_rt.w};

            accv0[p] += vxy * wxy0 + vzw * wzw0;
            accv1[p] += vxy * wxy1 + vzw * wzw1;
        }
    }
#pragma unroll
    for (int p = 0; p < 2; ++p) {
        outb[(h + p) * WW + w] = accv0[p].x + accv0[p].y;
        outb[HH * WW + (h + p) * WW + w] = accv1[p].x + accv1[p].y;
    }
}

// ---------------------------------------------------------------------------
extern "C" void kernel_launch(void* const* d_in, const int* in_sizes, int n_in,
                              void* d_out, int out_size, void* d_ws, size_t ws_size,
                              hipStream_t stream) {
    const float* rgb  = (const float*)d_in[0];
    const float* sar  = (const float*)d_in[1];
    const float* w_fm = (const float*)d_in[2];
    const float* w_fs = (const float*)d_in[3];
    const float* w_p  = (const float*)d_in[4];
    const float* b_p  = (const float*)d_in[5];
    const float* w_dc = (const float*)d_in[6];
    float* out = (float*)d_out;

    // ws layout: fm [131072 f32] | xp [B*HP*WP float4]
    float* ws = (float*)d_ws;
    float* fm = ws;
    float* xp = ws + 131072;                           // 16B aligned

    k_fm<<<BB * 128, 128, 0, stream>>>(rgb, w_fm, fm, (float4*)xp);
    k_mat<<<BB * (HH / ROWS), 128, 0, stream>>>(rgb, sar, w_fs, fm, xp);
    k_deform<<<dim3(HH / 4, BB), 256, 0, stream>>>(w_p, b_p, w_dc, xp, out);
}

// Round 11
// 64.390 us; speedup vs baseline: 2.4583x; 1.0725x over previous
//
#include <hip/hip_runtime.h>
#include <math.h>

typedef __attribute__((ext_vector_type(2))) _Float16 half2v;
typedef __attribute__((ext_vector_type(2))) float f32x2;
typedef __attribute__((ext_vector_type(4), aligned(8))) unsigned int uint4a;

#define BB 4
#define HH 2048
#define WW 128
#define HP (HH + 2)   // 2050
#define WP (WW + 2)   // 130
#define PP 128        // pooled size
#define ROWS 4

#define BORDER_PER_B (2 * WP + 2 * (HP - 2))   // 4356

__device__ __forceinline__ half2v b2h(unsigned u) { return __builtin_bit_cast(half2v, u); }
__device__ __forceinline__ unsigned pku(float a, float b) {
    return __builtin_bit_cast(unsigned, __builtin_amdgcn_cvt_pkrtz(a, b));
}
__device__ __forceinline__ float dot2(half2v a, unsigned wb, float c) {
    return __builtin_amdgcn_fdot2(a, b2h(wb), c, false);
}
__device__ __forceinline__ float hlo(unsigned u) { return (float)b2h(u).x; }
__device__ __forceinline__ float hhi(unsigned u) { return (float)b2h(u).y; }

// ---------------------------------------------------------------------------
// Kernel 1: border-zero of xph (fused) + adaptive avg pool + 1x1 conv + sigmoid
// ---------------------------------------------------------------------------
__global__ void k_fm(const float* __restrict__ rgb, const float* __restrict__ w_fm,
                     float* __restrict__ fm, uint2* __restrict__ xph) {
    int j = threadIdx.x;              // 0..127
    int bi = blockIdx.x;              // b*128 + i
    int tid = bi * 128 + j;

    if (tid < BB * BORDER_PER_B) {
        int b = tid / BORDER_PER_B;
        int r = tid - b * BORDER_PER_B;
        int row, col;
        if (r < WP)          { row = 0;      col = r; }
        else if (r < 2 * WP) { row = HP - 1; col = r - WP; }
        else {
            int q = r - 2 * WP;
            row = 1 + (q >> 1);
            col = (q & 1) ? (WP - 1) : 0;
        }
        xph[((size_t)b * HP + row) * WP + col] = make_uint2(0u, 0u);
    }

    int b = bi >> 7, i = bi & 127;
    const float* r0 = rgb + ((size_t)(b * 2 + 0) * HH + (size_t)i * 16) * WW + j;
    const float* r1 = rgb + ((size_t)(b * 2 + 1) * HH + (size_t)i * 16) * WW + j;
    float s0 = 0.f, s1 = 0.f;
#pragma unroll
    for (int a = 0; a < 16; ++a) { s0 += r0[a * WW]; s1 += r1[a * WW]; }
    s0 *= (1.f / 16.f); s1 *= (1.f / 16.f);
    float f0 = w_fm[0] * s0 + w_fm[1] * s1;
    float f1 = w_fm[2] * s0 + w_fm[3] * s1;
    fm[((size_t)(b * 2 + 0) * PP + i) * PP + j] = 1.f / (1.f + expf(-f0));
    fm[((size_t)(b * 2 + 1) * PP + i) * PP + j] = 1.f / (1.f + expf(-f1));
}

// ---------------------------------------------------------------------------
// Kernel 2: mat = rgb @ fm + rgb (per b,c), fs = w_fs @ mat,
//           pack xph cell = f16x4 (sar0,sar1,fs0,fs1) as uint2 (8B).
// ---------------------------------------------------------------------------
__global__ __launch_bounds__(128) void k_mat(
        const float* __restrict__ rgb, const float* __restrict__ sar,
        const float* __restrict__ w_fs, const float* __restrict__ fm,
        uint2* __restrict__ xph) {
    int w = threadIdx.x;              // 0..127
    int blk = blockIdx.x;
    int b = blk / (HH / ROWS);
    int h0 = (blk % (HH / ROWS)) * ROWS;

    const float* rg0 = rgb + ((size_t)(b * 2 + 0) * HH + h0) * WW;  // uniform base
    const float* rg1 = rgb + ((size_t)(b * 2 + 1) * HH + h0) * WW;
    const float* fm0 = fm + (size_t)(b * 2 + 0) * PP * PP;
    const float* fm1 = fm + (size_t)(b * 2 + 1) * PP * PP;

    float acc0[ROWS], acc1[ROWS];
#pragma unroll
    for (int r = 0; r < ROWS; ++r) {                 // residual term
        acc0[r] = rg0[r * WW + w];
        acc1[r] = rg1[r * WW + w];
    }

#pragma unroll 4
    for (int k4 = 0; k4 < PP; k4 += 4) {
        float f0[4], f1[4];
#pragma unroll
        for (int t = 0; t < 4; ++t) {
            f0[t] = fm0[(size_t)(k4 + t) * PP + w];  // coalesced vector load
            f1[t] = fm1[(size_t)(k4 + t) * PP + w];
        }
#pragma unroll
        for (int r = 0; r < ROWS; ++r) {
            float4 a0 = *(const float4*)(rg0 + r * WW + k4);   // uniform -> s_load
            float4 a1 = *(const float4*)(rg1 + r * WW + k4);
            acc0[r] += a0.x * f0[0] + a0.y * f0[1] + a0.z * f0[2] + a0.w * f0[3];
            acc1[r] += a1.x * f1[0] + a1.y * f1[1] + a1.z * f1[2] + a1.w * f1[3];
        }
    }

    float wa = w_fs[0], wb = w_fs[1], wc = w_fs[2], wd = w_fs[3];
#pragma unroll
    for (int r = 0; r < ROWS; ++r) {
        float m0 = acc0[r], m1 = acc1[r];
        float fs0 = wa * m0 + wb * m1;
        float fs1 = wc * m0 + wd * m1;
        float s0 = sar[((size_t)(b * 2 + 0) * HH + (h0 + r)) * WW + w];
        float s1 = sar[((size_t)(b * 2 + 1) * HH + (h0 + r)) * WW + w];
        uint2 cell = make_uint2(pku(s0, s1), pku(fs0, fs1));
        xph[((size_t)b * HP + (h0 + r + 1)) * WP + (w + 1)] = cell;
    }
}

// ---------------------------------------------------------------------------
// Kernel 3: offset conv (f32 pk_fma, exact offsets) + deformable bilinear in
// f16 (paired-row 16B gathers + cndmask x-select, dot2 combine). 2 px/thread.
// SGPR bases (blockIdx.y = batch). Single address stream (no dual paths).
// ---------------------------------------------------------------------------
__global__ __launch_bounds__(256, 3) void k_deform(
        const float* __restrict__ w_p, const float* __restrict__ b_p,
        const float* __restrict__ w_dc, const uint2* __restrict__ xph,
        float* __restrict__ out) {
    int b = blockIdx.y;                         // batch (uniform)
    int h0 = blockIdx.x * 4;                    // output rows h0..h0+3
    int tid = threadIdx.x;
    int w = tid & 127;
    int h = h0 + ((tid >> 7) << 1);             // this thread: rows h, h+1

    const uint2* xb = xph + (size_t)b * HP * WP;          // SGPR base
    const unsigned* xbu = (const unsigned*)xb;
    float* outb = out + (size_t)(b * 2) * HH * WW;        // SGPR base

    // 4 rows x 3 cols f16 neighborhood (8B cells)
    uint2 nbc[4][3];
#pragma unroll
    for (int dy = 0; dy < 4; ++dy)
#pragma unroll
        for (int dx = 0; dx < 3; ++dx)
            nbc[dy][dx] = xb[(h + dy) * WP + (w + dx)];

    // pixel-pair f32 vectors (cvt from f16), static indexing
    f32x2 prs[3][3][4];
#pragma unroll
    for (int ky = 0; ky < 3; ++ky)
#pragma unroll
        for (int kx = 0; kx < 3; ++kx) {
            uint2 cA = nbc[ky][kx], cB = nbc[ky + 1][kx];
            prs[ky][kx][0] = (f32x2){hlo(cA.x), hlo(cB.x)};
            prs[ky][kx][1] = (f32x2){hhi(cA.x), hhi(cB.x)};
            prs[ky][kx][2] = (f32x2){hlo(cA.y), hlo(cB.y)};
            prs[ky][kx][3] = (f32x2){hhi(cA.y), hhi(cB.y)};
        }

    // ---- offset conv: r-outer, local accumulator -> v_pk_fma_f32 ----
    f32x2 off2[18];
#pragma unroll
    for (int r = 0; r < 18; ++r) {
        float bias = b_p[r];                    // uniform -> s_load (input buf)
        f32x2 s = (f32x2){bias, bias};
#pragma unroll
        for (int ky = 0; ky < 3; ++ky)
#pragma unroll
            for (int kx = 0; kx < 3; ++kx) {
                const float* wr = w_p + r * 36 + ky * 3 + kx;  // uniform s_load
                s += wr[0] * prs[ky][kx][0] + wr[9] * prs[ky][kx][1]
                   + wr[18] * prs[ky][kx][2] + wr[27] * prs[ky][kx][3];
            }
        off2[r] = s;
    }

    float acc0[2] = {0.f, 0.f};
    float acc1[2] = {0.f, 0.f};
#pragma unroll
    for (int n = 0; n < 9; ++n) {
        int pny = n / 3 - 1;
        int pnx = n % 3 - 1;
        // packed coordinates for the pixel pair (f32 exact)
        f32x2 py2 = (f32x2){(float)(h + 1 + pny), (float)(h + 2 + pny)} + off2[n];
        f32x2 px2 = (float)(w + 1 + pnx) + off2[9 + n];
        f32x2 fy2 = {floorf(py2.x), floorf(py2.y)};
        f32x2 fx2 = {floorf(px2.x), floorf(px2.y)};
        f32x2 y0f = {fminf(fmaxf(fy2.x, 0.f), (float)(HP - 1)),
                     fminf(fmaxf(fy2.y, 0.f), (float)(HP - 1))};
        f32x2 y1f = {fminf(fmaxf(fy2.x + 1.f, 0.f), (float)(HP - 1)),
                     fminf(fmaxf(fy2.y + 1.f, 0.f), (float)(HP - 1))};
        f32x2 x0f = {fminf(fmaxf(fx2.x, 0.f), (float)(WP - 1)),
                     fminf(fmaxf(fx2.y, 0.f), (float)(WP - 1))};
        f32x2 x1f = {fminf(fmaxf(fx2.x + 1.f, 0.f), (float)(WP - 1)),
                     fminf(fmaxf(fx2.y + 1.f, 0.f), (float)(WP - 1))};
        f32x2 pyc = {fminf(fmaxf(py2.x, 0.f), (float)(HP - 1)),
                     fminf(fmaxf(py2.y, 0.f), (float)(HP - 1))};
        f32x2 pxc = {fminf(fmaxf(px2.x, 0.f), (float)(WP - 1)),
                     fminf(fmaxf(px2.y, 0.f), (float)(WP - 1))};
        f32x2 ay = 1.f + (y0f - pyc);
        f32x2 by = 1.f - (y1f - pyc);
        f32x2 ax = 1.f + (x0f - pxc);
        f32x2 bx = 1.f - (x1f - pxc);
        f32x2 glt = ay * ax, grb = by * bx, glb = ay * bx, grt = by * ax;

        // deform-conv weight packs (from uniform s_loads), shared over p
        unsigned wd00 = pku(w_dc[0 * 36 + 0 * 9 + n], w_dc[0 * 36 + 1 * 9 + n]);
        unsigned wd01 = pku(w_dc[0 * 36 + 2 * 9 + n], w_dc[0 * 36 + 3 * 9 + n]);
        unsigned wd10 = pku(w_dc[1 * 36 + 0 * 9 + n], w_dc[1 * 36 + 1 * 9 + n]);
        unsigned wd11 = pku(w_dc[1 * 36 + 2 * 9 + n], w_dc[1 * 36 + 3 * 9 + n]);

#pragma unroll
        for (int p = 0; p < 2; ++p) {           // p compile-time
            int y0 = (int)(p ? y0f.y : y0f.x);
            int y1 = (int)(p ? y1f.y : y1f.x);
            int x0 = (int)(p ? x0f.y : x0f.x);
            int x1 = (int)(p ? x1f.y : x1f.x);
            float g_lt = p ? glt.y : glt.x;
            float g_rb = p ? grb.y : grb.x;
            float g_lb = p ? glb.y : glb.x;
            float g_rt = p ? grt.y : grt.x;

            // paired-row 16B loads: cells (y,x0) and (y,x0+1)
            uint4a q0 = *(const uint4a*)(xbu + 2 * (y0 * WP + x0));
            uint4a q1 = *(const uint4a*)(xbu + 2 * (y1 * WP + x0));
            bool adj = (x1 > x0);               // x1 == x0+1 ? (else clamp: x1==x0)
            unsigned lt01 = q0.x, lt23 = q0.y;
            unsigned lb01 = adj ? q0.z : q0.x, lb23 = adj ? q0.w : q0.y;
            unsigned rt01 = q1.x, rt23 = q1.y;
            unsigned rb01 = adj ? q1.z : q1.x, rb23 = adj ? q1.w : q1.y;

            unsigned glt_h = pku(g_lt, g_lt);
            unsigned grb_h = pku(g_rb, g_rb);
            unsigned glb_h = pku(g_lb, g_lb);
            unsigned grt_h = pku(g_rt, g_rt);

            half2v h01 = b2h(glt_h) * b2h(lt01) + b2h(grb_h) * b2h(rb01)
                       + b2h(glb_h) * b2h(lb01) + b2h(grt_h) * b2h(rt01);
            half2v h23 = b2h(glt_h) * b2h(lt23) + b2h(grb_h) * b2h(rb23)
                       + b2h(glb_h) * b2h(lb23) + b2h(grt_h) * b2h(rt23);

            acc0[p] = dot2(h01, wd00, acc0[p]);
            acc0[p] = dot2(h23, wd01, acc0[p]);
            acc1[p] = dot2(h01, wd10, acc1[p]);
            acc1[p] = dot2(h23, wd11, acc1[p]);
        }
    }
#pragma unroll
    for (int p = 0; p < 2; ++p) {
        outb[(h + p) * WW + w] = acc0[p];
        outb[HH * WW + (h + p) * WW + w] = acc1[p];
    }
}

// ---------------------------------------------------------------------------
extern "C" void kernel_launch(void* const* d_in, const int* in_sizes, int n_in,
                              void* d_out, int out_size, void* d_ws, size_t ws_size,
                              hipStream_t stream) {
    const float* rgb  = (const float*)d_in[0];
    const float* sar  = (const float*)d_in[1];
    const float* w_fm = (const float*)d_in[2];
    const float* w_fs = (const float*)d_in[3];
    const float* w_p  = (const float*)d_in[4];
    const float* b_p  = (const float*)d_in[5];
    const float* w_dc = (const float*)d_in[6];
    float* out = (float*)d_out;

    // ws layout: fm [131072 f32] | xph [BB*HP*WP uint2 + 2 slack cells]
    float* ws = (float*)d_ws;
    float* fm = ws;
    uint2* xph = (uint2*)(ws + 131072);                // 8B aligned

    k_fm<<<BB * 128, 128, 0, stream>>>(rgb, w_fm, fm, xph);
    k_mat<<<BB * (HH / ROWS), 128, 0, stream>>>(rgb, sar, w_fs, fm, xph);
    k_deform<<<dim3(HH / 4, BB), 256, 0, stream>>>(w_p, b_p, w_dc, xph, out);
}